// Round 4
// baseline (294.977 us; speedup 1.0000x reference)
//
#include <hip/hip_runtime.h>

// out = tile(v, 16) where v = x @ Wv^T + bv  (softmax over singleton axis == 1)
// x: [16384][2048] fp32, Wv = Wkv[128:256][:], bv = bkv[128:256]
// out[row][h*128+d] = v[row][d] for h=0..15 (fp32)
//
// R4 structure: NO LDS staging, NO barriers in the K-loop. Each wave is
// independent: A fragments straight from global (dwordx4, line-covering),
// B fragments straight from fragment-packed L2-resident Wvp (1 KiB/instr).
// Latency hidden by TLP: 1024 blocks x 4 waves = 16 waves/CU.

typedef __attribute__((ext_vector_type(8))) short bf16x8;
typedef __attribute__((ext_vector_type(4))) float f32x4;

#define M_TOTAL 16384
#define K_DIM   2048
#define BM      16
#define NT      32            // k-tiles of 64

__device__ __forceinline__ unsigned short f2bf(float f) {
    unsigned int u = __float_as_uint(f);
    u += 0x7FFFu + ((u >> 16) & 1u);   // RNE
    return (unsigned short)(u >> 16);
}

// Pack V-half of Wkv into MFMA-fragment order, bf16:
// Wvp[t][cb][lane][8], cb = ks*8 + c; element = Wv[c*16 + (lane&15)]
//                                               [t*64 + ks*32 + (lane>>4)*8 + e]
__global__ void prep_wv(const float* __restrict__ Wkv, unsigned short* __restrict__ Wvp) {
    const int tid = blockIdx.x * 256 + threadIdx.x;   // 0..32767
    const int l  = tid & 63;
    const int cb = (tid >> 6) & 15;
    const int t  = tid >> 10;
    const int c  = cb & 7, ks = cb >> 3;
    const int col   = c * 16 + (l & 15);
    const int kbase = t * 64 + ks * 32 + (l >> 4) * 8;
    const float* src = Wkv + (size_t)(128 + col) * K_DIM + kbase;
    const float4 f0 = *reinterpret_cast<const float4*>(src);
    const float4 f1 = *reinterpret_cast<const float4*>(src + 4);
    ushort4 o0 = { f2bf(f0.x), f2bf(f0.y), f2bf(f0.z), f2bf(f0.w) };
    ushort4 o1 = { f2bf(f1.x), f2bf(f1.y), f2bf(f1.z), f2bf(f1.w) };
    ushort4* dst = reinterpret_cast<ushort4*>(Wvp + (size_t)tid * 8);
    dst[0] = o0; dst[1] = o1;
}

__device__ __forceinline__ bf16x8 cvt_frag(float4 lo, float4 hi) {
    union { unsigned int u[4]; bf16x8 v; } r;
    asm("v_cvt_pk_bf16_f32 %0, %1, %2" : "=v"(r.u[0]) : "v"(lo.x), "v"(lo.y));
    asm("v_cvt_pk_bf16_f32 %0, %1, %2" : "=v"(r.u[1]) : "v"(lo.z), "v"(lo.w));
    asm("v_cvt_pk_bf16_f32 %0, %1, %2" : "=v"(r.u[2]) : "v"(hi.x), "v"(hi.y));
    asm("v_cvt_pk_bf16_f32 %0, %1, %2" : "=v"(r.u[3]) : "v"(hi.z), "v"(hi.w));
    return r.v;
}

__global__ __launch_bounds__(256) void mqa_v_gemm(
    const float* __restrict__ x,
    const unsigned short* __restrict__ Wvp,
    const float* __restrict__ bkv,
    float* __restrict__ out)
{
    __shared__ __align__(16) float vl[BM][132];   // epilogue broadcast only

    const int tid  = threadIdx.x;
    const int l    = tid & 63;
    const int w    = tid >> 6;            // wave 0..3 -> cols [32w, 32w+32)
    const int frow = l & 15;              // A row / C col index
    const int fg   = l >> 4;              // k-group (8 elems)
    const size_t row0 = (size_t)blockIdx.x * BM;

    // A: lane (frow,fg) reads x[row0+frow][t*64 + ks*32 + fg*8 .. +8]
    const float* gA = x + (row0 + frow) * (size_t)K_DIM + fg * 8;
    // B: fragment (t,ks,c) is 1 KiB at Wvp + ((t*16 + ks*8 + c)*64 + l)*8
    const unsigned short* gB = Wvp + (size_t)l * 8;

    f32x4 acc0 = {0.f, 0.f, 0.f, 0.f};
    f32x4 acc1 = {0.f, 0.f, 0.f, 0.f};

    #pragma unroll 4
    for (int t = 0; t < NT; ++t) {
        const float* at = gA + t * 64;
        const float4 a0lo = *reinterpret_cast<const float4*>(at);
        const float4 a0hi = *reinterpret_cast<const float4*>(at + 4);
        const float4 a1lo = *reinterpret_cast<const float4*>(at + 32);
        const float4 a1hi = *reinterpret_cast<const float4*>(at + 36);
        const bf16x8 b00 = *reinterpret_cast<const bf16x8*>(gB + ((t * 16 +     2 * w    ) << 9));
        const bf16x8 b01 = *reinterpret_cast<const bf16x8*>(gB + ((t * 16 +     2 * w + 1) << 9));
        const bf16x8 b10 = *reinterpret_cast<const bf16x8*>(gB + ((t * 16 + 8 + 2 * w    ) << 9));
        const bf16x8 b11 = *reinterpret_cast<const bf16x8*>(gB + ((t * 16 + 8 + 2 * w + 1) << 9));

        const bf16x8 a0 = cvt_frag(a0lo, a0hi);
        const bf16x8 a1 = cvt_frag(a1lo, a1hi);

        acc0 = __builtin_amdgcn_mfma_f32_16x16x32_bf16(a0, b00, acc0, 0, 0, 0);
        acc1 = __builtin_amdgcn_mfma_f32_16x16x32_bf16(a0, b01, acc1, 0, 0, 0);
        acc0 = __builtin_amdgcn_mfma_f32_16x16x32_bf16(a1, b10, acc0, 0, 0, 0);
        acc1 = __builtin_amdgcn_mfma_f32_16x16x32_bf16(a1, b11, acc1, 0, 0, 0);
    }

    // ---- epilogue: bias, stage v row-tile, broadcast 16x ----
    // C/D layout: col = lane&15, row = (lane>>4)*4 + j  [m89-verified]
    const int c0 = w * 32 + frow;
    const int c1 = c0 + 16;
    const float bias0 = bkv[128 + c0];
    const float bias1 = bkv[128 + c1];
    #pragma unroll
    for (int j = 0; j < 4; ++j) {
        const int r = fg * 4 + j;
        vl[r][c0] = acc0[j] + bias0;
        vl[r][c1] = acc1[j] + bias1;
    }
    __syncthreads();

    // replicated, fully-coalesced float4 output (each out row = 16 copies of v row)
    float4* op = reinterpret_cast<float4*>(out + row0 * K_DIM);
    #pragma unroll
    for (int i = tid; i < BM * (K_DIM / 4); i += 256) {
        const int r  = i >> 9;               // 512 float4 per output row
        const int c4 = i & 31;               // float4 index within one 128-wide copy
        op[i] = *reinterpret_cast<const float4*>(&vl[r][c4 << 2]);
    }
}

extern "C" void kernel_launch(void* const* d_in, const int* in_sizes, int n_in,
                              void* d_out, int out_size, void* d_ws, size_t ws_size,
                              hipStream_t stream)
{
    const float* x   = (const float*)d_in[0];
    // d_in[1] = Wq, d_in[2] = bq : dead (softmax over singleton axis == 1)
    const float* Wkv = (const float*)d_in[3];
    const float* bkv = (const float*)d_in[4];
    float* out       = (float*)d_out;
    unsigned short* Wvp = (unsigned short*)d_ws;   // 512 KiB fragment-packed bf16

    prep_wv<<<128, 256, 0, stream>>>(Wkv, Wvp);
    mqa_v_gemm<<<M_TOTAL / BM, 256, 0, stream>>>(x, Wvp, bkv, out);
}